// Round 11
// baseline (37545.972 us; speedup 1.0000x reference)
//
#include <hip/hip_runtime.h>
#include <hip/hip_bf16.h>

#define N_NODES 16384
#define E_EDGESN (16384*32)
#define FEAT 512
#define EMB 256
#define HID 512
#define G4 2048      // 4*HID
#define XDIM 512     // 2*EMB
#define NWG 128      // worker workgroups (single wave each)
#define UPW 4        // hidden units per wg (4 x 128 = 512)
#define NREP 8       // mailbox replicas
#define REPW 4096    // replica stride in words (16 KB)

typedef __attribute__((ext_vector_type(8))) short bf16x8;
typedef __attribute__((ext_vector_type(4))) float f32x4;

__device__ __forceinline__ float b2f(unsigned short u) {
  union { unsigned int i; float f; } v; v.i = ((unsigned int)u) << 16; return v.f;
}
__device__ __forceinline__ unsigned short f2b(float f) {
  union { float f; unsigned int i; } v; v.f = f;
  unsigned int x = v.i;
  unsigned int r = (x + 0x7FFFu + ((x >> 16) & 1u)) >> 16;
  return (unsigned short)r;
}
__device__ __forceinline__ float fast_sigmoid(float x) {
  return __builtin_amdgcn_rcpf(1.0f + __expf(-x));
}
__device__ __forceinline__ float fast_tanh(float x) {
  return fmaf(-2.0f, __builtin_amdgcn_rcpf(1.0f + __expf(2.0f * x)), 1.0f);
}

// ---------------- K0: dtype detection (bf16 vs fp32 inputs) ----------------
__global__ __launch_bounds__(256) void k_detect(const unsigned* __restrict__ w,
                                                unsigned* __restrict__ flag) {
  __shared__ int cnt;
  if (threadIdx.x == 0) cnt = 0;
  __syncthreads();
  int hits = 0;
#pragma unroll
  for (int j = 0; j < 4; ++j) {
    unsigned wv = w[threadIdx.x * 4 + j];
    unsigned e = (wv >> 7) & 0xFFu;
    if ((e >= 90u && e <= 126u) || ((wv & 0xFFFFu) == 0u)) hits++;
  }
  atomicAdd(&cnt, hits);
  __syncthreads();
  if (threadIdx.x == 0) *flag = (cnt < 512) ? 1u : 0u;   // 1 = fp32 inputs
}

// ---------------- K1: canonicalize float tensor to bf16 ----------------
__global__ void k_convert(const void* __restrict__ src, unsigned short* __restrict__ dst,
                          int n, const unsigned* __restrict__ flag) {
  int i = blockIdx.x * blockDim.x + threadIdx.x;
  if (i >= n) return;
  if (*flag) dst[i] = f2b(((const float*)src)[i]);
  else       dst[i] = ((const unsigned short*)src)[i];
}

// ---------------- K2: tag histogram scatter ----------------
__global__ void k_hist(const int* __restrict__ nid, const int* __restrict__ ntag,
                       unsigned* __restrict__ hist) {
  int e = blockIdx.x * blockDim.x + threadIdx.x;
  if (e < E_EDGESN)
    atomicAdd(&hist[(size_t)nid[e] * FEAT + ntag[e]], 1u);
}

// ---------------- K3: build x = [node_emb | nb_emb] as bf16 ----------------
__global__ __launch_bounds__(256) void k_build_x(
    const int* __restrict__ tags, const unsigned* __restrict__ hist,
    const unsigned short* __restrict__ Wemb, const unsigned short* __restrict__ bemb,
    unsigned short* __restrict__ x) {
  __shared__ int f_lds[160];
  __shared__ float c_lds[160];
  __shared__ int nlist;
  int n = blockIdx.x, c = threadIdx.x;
  if (c == 0) nlist = 0;
  __syncthreads();
  for (int f = c; f < FEAT; f += 256) {
    unsigned cnt = hist[(size_t)n * FEAT + f];
    if (cnt) {
      int idx = atomicAdd(&nlist, 1);
      if (idx < 160) { f_lds[idx] = f; c_lds[idx] = (float)cnt; }
    }
  }
  __syncthreads();
  int m = nlist; if (m > 160) m = 160;
  float be = b2f(bemb[c]);
  int tg = tags[n];
  x[(size_t)n * XDIM + c] = f2b(b2f(Wemb[(size_t)tg * EMB + c]) + be);
  float acc = be;
  for (int j = 0; j < m; ++j)
    acc += c_lds[j] * b2f(Wemb[(size_t)f_lds[j] * EMB + c]);
  x[(size_t)n * XDIM + EMB + c] = f2b(acc);
}

// ---------------- K4: pre = x @ W_ih^T + b_lstm (MFMA bf16) ----------------
// Output PERMUTED: prep[t][unit*4 + gate]; gate = nn>>9, unit = nn&511.
__global__ __launch_bounds__(256) void k_gemm_pre(
    const unsigned short* __restrict__ x, const unsigned short* __restrict__ Wih,
    const unsigned short* __restrict__ blstm, unsigned short* __restrict__ pre) {
  int wave = threadIdx.x >> 6, lane = threadIdx.x & 63;
  int row = lane & 15, quad = lane >> 4;
  int mband = blockIdx.y * 64 + wave * 16;
  int nbase = blockIdx.x * 128;
  f32x4 acc[8] = {};
  const unsigned short* ap = x + (size_t)(mband + row) * XDIM + quad * 8;
  const unsigned short* bp0 = Wih + (size_t)(nbase + row) * XDIM + quad * 8;
  for (int kc = 0; kc < 16; ++kc) {
    bf16x8 af = *(const bf16x8*)(ap + kc * 32);
#pragma unroll
    for (int nt = 0; nt < 8; ++nt) {
      bf16x8 bf = *(const bf16x8*)(bp0 + (size_t)nt * 16 * XDIM + kc * 32);
      acc[nt] = __builtin_amdgcn_mfma_f32_16x16x32_bf16(af, bf, acc[nt], 0, 0, 0);
    }
  }
#pragma unroll
  for (int nt = 0; nt < 8; ++nt) {
    int nn = nbase + nt * 16 + row;
    float bv = b2f(blstm[nn]);
    int pn = ((nn & 511) << 2) | (nn >> 9);   // unit*4 + gate
#pragma unroll
    for (int i = 0; i < 4; ++i) {
      int mm = mband + quad * 4 + i;
      pre[(size_t)mm * G4 + pn] = f2b(acc[nt][i] + bv);
    }
  }
}

// ---------------- K5: single-wave replicated-mailbox LSTM scan (v11) -------
// 128 wgs x 64 thr (ONE wave each -> no __syncthreads anywhere in the loop;
// LDS producer/consumer ordering is wave-lockstep + lgkmcnt).
// 16-lane group owns one unit (4 of them per wg); 128 fp32 W_hh weights in
// VGPRs, k interleaved k = 32j + 2s + {0,1} (conflict-free float2 matvec).
// h publication: ONE word/unit = (fp32 h & 0xFFFFFF00) | (t & 0xFF)
//   (validated r9/r10). 8 replica mailboxes, 16 KB apart. Gates computed
//   redundantly on all 16 lanes -> lanes s<8 store one replica each (all 32
//   stores of a wg issue in parallel).
// consumer: each lane polls its own 8 words = 4x 8-B agent-scope relaxed
//   atomic loads (proven encoding; compiler batches 4 in flight, one wait),
//   then writes 8 h-floats straight to LDS. 2-slot ring induction unchanged.
// pre: staged 8 steps/block into LDS; global load ISSUED before the poll,
//   LDS write after -> latency hidden behind the poll.
__global__ __launch_bounds__(64, 1) void k_scan(
    const unsigned short* __restrict__ Whh, const unsigned short* __restrict__ prep,
    unsigned* __restrict__ hw, float* __restrict__ embed) {
  __shared__ float h_lds[HID];
  __shared__ unsigned pre_s[64];
  int lane = threadIdx.x;      // 0..63
  int wg = blockIdx.x;
  int ug = lane >> 4;          // unit in wg [0,4)
  int s  = lane & 15;          // k-slice
  int unit = wg * UPW + ug;    // global unit [0,512)

  // W_hh rows for this unit's 4 gates, k interleaved: k = 32j + 2s + {0,1}
  float wreg[4][32];
#pragma unroll
  for (int g = 0; g < 4; ++g) {
    const unsigned* wp = (const unsigned*)(Whh + (size_t)(g * HID + unit) * HID);
#pragma unroll
    for (int j = 0; j < 16; ++j) {
      unsigned wv = wp[16 * j + s];
      wreg[g][2 * j]     = b2f((unsigned short)(wv & 0xFFFFu));
      wreg[g][2 * j + 1] = b2f((unsigned short)(wv >> 16));
    }
  }

  const unsigned* prep32 = (const unsigned*)prep;
  // stage pre for steps 0..7: lane<32 loads one 8-B chunk (row=lane>>2, w=2*(lane&3))
  if (lane < 32) {
    int row = lane >> 2;
    ((unsigned long long*)pre_s)[lane] =
        *(const unsigned long long*)(prep32 + (size_t)row * 1024 + wg * 8 + 2 * (lane & 3));
  }
  // h(-1) = 0
  ((float4*)h_lds)[lane * 2]     = make_float4(0.f, 0.f, 0.f, 0.f);
  ((float4*)h_lds)[lane * 2 + 1] = make_float4(0.f, 0.f, 0.f, 0.f);

  float cstate = 0.0f, eacc = 0.0f;
  unsigned myrep = (unsigned)(wg & (NREP - 1));

  for (int t = 0; t < N_NODES; ++t) {
    // ---- matvec over h(t-1): conflict-free float2, broadcast across groups ----
    float a0 = 0.f, a1 = 0.f, a2 = 0.f, a3 = 0.f;
    const float2* hb = (const float2*)h_lds;
#pragma unroll
    for (int j = 0; j < 16; ++j) {
      float2 hv = hb[j * 16 + s];
      a0 += wreg[0][2*j] * hv.x + wreg[0][2*j+1] * hv.y;
      a1 += wreg[1][2*j] * hv.x + wreg[1][2*j+1] * hv.y;
      a2 += wreg[2][2*j] * hv.x + wreg[2][2*j+1] * hv.y;
      a3 += wreg[3][2*j] * hv.x + wreg[3][2*j+1] * hv.y;
    }
#pragma unroll
    for (int off = 1; off < 16; off <<= 1) {
      a0 += __shfl_xor(a0, off);   // all 16 lanes of a group end identical
      a1 += __shfl_xor(a1, off);
      a2 += __shfl_xor(a2, off);
      a3 += __shfl_xor(a3, off);
    }

    int p = t & 7;
    unsigned w0 = pre_s[8 * p + 2 * ug];
    unsigned w1 = pre_s[8 * p + 2 * ug + 1];

    // gates redundantly on all 16 lanes -> bit-identical cstate/hn per group
    float gi = fast_sigmoid(a0 + b2f((unsigned short)(w0 & 0xFFFFu)));
    float gf = fast_sigmoid(a1 + b2f((unsigned short)(w0 >> 16)));
    float gg = fast_tanh   (a2 + b2f((unsigned short)(w1 & 0xFFFFu)));
    float go = fast_sigmoid(a3 + b2f((unsigned short)(w1 >> 16)));
    cstate = gf * cstate + gi * gg;
    float hn = go * fast_tanh(cstate);
    if (s == 0) eacc += hn;

    // issue next pre-block load BEFORE the poll (latency hidden behind poll)
    unsigned long long stg = 0;
    int do_stage = (p == 7) && (lane < 32);
    if (do_stage) {
      int row = t + 1 + (lane >> 2);
      if (row >= N_NODES) row = 0;
      stg = *(const unsigned long long*)(prep32 + (size_t)row * 1024 + wg * 8 + 2 * (lane & 3));
    }

    if (t < N_NODES - 1) {
      unsigned tagw = (unsigned)t & 0xFFu;
      unsigned slotw = ((unsigned)t & 1u) << 9;
      union { float f; unsigned u; } cu; cu.f = hn;
      unsigned word = (cu.u & 0xFFFFFF00u) | tagw;
      if (s < 8)   // replica s: 32 parallel stores per wg (4 units x 8 reps)
        __hip_atomic_store(&hw[(unsigned)s * REPW + slotw + (unsigned)unit], word,
                           __ATOMIC_RELAXED, __HIP_MEMORY_SCOPE_AGENT);

      // poll own 8 words (units [8*lane, 8*lane+8)) from replica myrep
      unsigned long long* qp =
          (unsigned long long*)(hw + myrep * REPW + slotw) + lane * 4;
      unsigned long long tp = (unsigned long long)tagw * 0x0000000100000001ULL;
      unsigned long long v0, v1, v2, v3;
      int tries = 0;
      for (;;) {
        v0 = __hip_atomic_load(qp + 0, __ATOMIC_RELAXED, __HIP_MEMORY_SCOPE_AGENT);
        v1 = __hip_atomic_load(qp + 1, __ATOMIC_RELAXED, __HIP_MEMORY_SCOPE_AGENT);
        v2 = __hip_atomic_load(qp + 2, __ATOMIC_RELAXED, __HIP_MEMORY_SCOPE_AGENT);
        v3 = __hip_atomic_load(qp + 3, __ATOMIC_RELAXED, __HIP_MEMORY_SCOPE_AGENT);
        unsigned long long d = ((v0 ^ tp) | (v1 ^ tp) | (v2 ^ tp) | (v3 ^ tp))
                               & 0x000000FF000000FFULL;
        if (d == 0ULL) break;
        if (++tries > 96) __builtin_amdgcn_s_sleep(1);
      }
      float4 f0, f1;
      f0.x = __uint_as_float((unsigned)v0 & 0xFFFFFF00u);
      f0.y = __uint_as_float((unsigned)(v0 >> 32) & 0xFFFFFF00u);
      f0.z = __uint_as_float((unsigned)v1 & 0xFFFFFF00u);
      f0.w = __uint_as_float((unsigned)(v1 >> 32) & 0xFFFFFF00u);
      f1.x = __uint_as_float((unsigned)v2 & 0xFFFFFF00u);
      f1.y = __uint_as_float((unsigned)(v2 >> 32) & 0xFFFFFF00u);
      f1.z = __uint_as_float((unsigned)v3 & 0xFFFFFF00u);
      f1.w = __uint_as_float((unsigned)(v3 >> 32) & 0xFFFFFF00u);
      ((float4*)h_lds)[lane * 2]     = f0;   // wave-lockstep: matvec of step t
      ((float4*)h_lds)[lane * 2 + 1] = f1;   // already read h_lds (program order)
    }
    if (do_stage)
      ((unsigned long long*)pre_s)[lane] = stg;   // vmcnt drained by poll
  }
  if (s == 0) embed[unit] = eacc;
}

// ---------------- K6: MLP head + log_softmax ----------------
__global__ __launch_bounds__(512) void k_head(
    const float* __restrict__ embed, const unsigned short* __restrict__ W1,
    const unsigned short* __restrict__ b1, const unsigned short* __restrict__ W2,
    const unsigned short* __restrict__ b2, void* __restrict__ out,
    const unsigned* __restrict__ flag) {
  __shared__ float e_s[HID], h1_s[HID];
  __shared__ float lg[16];
  int tid = threadIdx.x;
  e_s[tid] = embed[tid];
  __syncthreads();
  float sum = b2f(b1[tid]);
  for (int i = 0; i < HID; ++i)
    sum += e_s[i] * b2f(W1[(size_t)i * HID + tid]);
  h1_s[tid] = fmaxf(sum, 0.0f);
  __syncthreads();
  if (tid < 10) {
    float l = b2f(b2[tid]);
    for (int j = 0; j < HID; ++j)
      l += h1_s[j] * b2f(W2[(size_t)j * 10 + tid]);
    lg[tid] = l;
  }
  __syncthreads();
  if (tid == 0) {
    float m = -1e30f;
    for (int c = 0; c < 10; ++c) m = fmaxf(m, lg[c]);
    float se = 0.f;
    for (int c = 0; c < 10; ++c) se += expf(lg[c] - m);
    float lse = m + logf(se);
    if (*flag) {
      for (int c = 0; c < 10; ++c) ((float*)out)[c] = lg[c] - lse;
    } else {
      for (int c = 0; c < 10; ++c) ((unsigned short*)out)[c] = f2b(lg[c] - lse);
    }
  }
}

extern "C" void kernel_launch(void* const* d_in, const int* in_sizes, int n_in,
                              void* d_out, int out_size, void* d_ws, size_t ws_size,
                              hipStream_t stream) {
  const int* node_tags = (const int*)d_in[0];
  const int* nid = (const int*)d_in[1];
  const int* ntag = (const int*)d_in[2];
  // d_in[3] = label, unused

  char* ws = (char*)d_ws;
  unsigned short* pre  = (unsigned short*)ws;                     // 67,108,864
  unsigned short* x    = (unsigned short*)(ws + 67108864);        // 16,777,216
  unsigned*       hist = (unsigned*)(ws + 83886080);              // 33,554,432
  char* tail = ws + 117440512;
  unsigned* hw    = (unsigned*)tail;                              // 128 KB: 8 replicas x 16 KB (NOT zeroed - poison-safe, see k_scan)
  unsigned* flag  = (unsigned*)(tail + 131072);
  float*    embed = (float*)(tail + 131328);                      // 2048 B
  char* wc = tail + 135168;                                       // bf16 weight copies
  unsigned short* Wemb_c  = (unsigned short*)(wc);
  unsigned short* bemb_c  = (unsigned short*)(wc + 262144);
  unsigned short* Wih_c   = (unsigned short*)(wc + 262656);
  unsigned short* Whh_c   = (unsigned short*)(wc + 2359808);
  unsigned short* blstm_c = (unsigned short*)(wc + 4456960);
  unsigned short* W1_c    = (unsigned short*)(wc + 4461056);
  unsigned short* b1_c    = (unsigned short*)(wc + 4985344);
  unsigned short* W2_c    = (unsigned short*)(wc + 4986368);
  unsigned short* b2_c    = (unsigned short*)(wc + 4996608);

  hipMemsetAsync(hist, 0, 33554432, stream);   // hist must start at zero

  k_detect<<<1, 256, 0, stream>>>((const unsigned*)d_in[6], flag);

  struct { const void* s; unsigned short* d; int n; } cv[9] = {
    { d_in[4],  Wemb_c,  FEAT * EMB },
    { d_in[5],  bemb_c,  EMB },
    { d_in[6],  Wih_c,   G4 * XDIM },
    { d_in[7],  Whh_c,   G4 * HID },
    { d_in[8],  blstm_c, G4 },
    { d_in[9],  W1_c,    HID * HID },
    { d_in[10], b1_c,    HID },
    { d_in[11], W2_c,    HID * 10 },
    { d_in[12], b2_c,    10 },
  };
  for (int i = 0; i < 9; ++i)
    k_convert<<<(cv[i].n + 255) / 256, 256, 0, stream>>>(cv[i].s, cv[i].d, cv[i].n, flag);

  k_hist<<<E_EDGESN / 256, 256, 0, stream>>>(nid, ntag, hist);
  k_build_x<<<N_NODES, 256, 0, stream>>>(node_tags, hist, Wemb_c, bemb_c, x);
  k_gemm_pre<<<dim3(G4 / 128, N_NODES / 64), 256, 0, stream>>>(x, Wih_c, blstm_c, pre);
  k_scan<<<NWG, 64, 0, stream>>>(Whh_c, pre, hw, embed);
  k_head<<<1, 512, 0, stream>>>(embed, W1_c, b1_c, W2_c, b2_c, d_out, flag);
}

// Round 12
// 31511.710 us; speedup vs baseline: 1.1915x; 1.1915x over previous
//
#include <hip/hip_runtime.h>
#include <hip/hip_bf16.h>

#define N_NODES 16384
#define E_EDGESN (16384*32)
#define FEAT 512
#define EMB 256
#define HID 512
#define G4 2048      // 4*HID
#define XDIM 512     // 2*EMB
#define NWG 32       // worker workgroups
#define UPW 16       // hidden units per wg (16 x 32 = 512)
#define NREP 8       // mailbox replicas (LLC slice spreading; r12: 4->8)
#define REPW 4096    // replica stride in words (16 KB)

typedef __attribute__((ext_vector_type(8))) short bf16x8;
typedef __attribute__((ext_vector_type(4))) float f32x4;

__device__ __forceinline__ float b2f(unsigned short u) {
  union { unsigned int i; float f; } v; v.i = ((unsigned int)u) << 16; return v.f;
}
__device__ __forceinline__ unsigned short f2b(float f) {
  union { float f; unsigned int i; } v; v.f = f;
  unsigned int x = v.i;
  unsigned int r = (x + 0x7FFFu + ((x >> 16) & 1u)) >> 16;
  return (unsigned short)r;
}
__device__ __forceinline__ float fast_sigmoid(float x) {
  return __builtin_amdgcn_rcpf(1.0f + __expf(-x));
}
__device__ __forceinline__ float fast_tanh(float x) {
  return fmaf(-2.0f, __builtin_amdgcn_rcpf(1.0f + __expf(2.0f * x)), 1.0f);
}

// ---------------- K0: dtype detection (bf16 vs fp32 inputs) ----------------
__global__ __launch_bounds__(256) void k_detect(const unsigned* __restrict__ w,
                                                unsigned* __restrict__ flag) {
  __shared__ int cnt;
  if (threadIdx.x == 0) cnt = 0;
  __syncthreads();
  int hits = 0;
#pragma unroll
  for (int j = 0; j < 4; ++j) {
    unsigned wv = w[threadIdx.x * 4 + j];
    unsigned e = (wv >> 7) & 0xFFu;
    if ((e >= 90u && e <= 126u) || ((wv & 0xFFFFu) == 0u)) hits++;
  }
  atomicAdd(&cnt, hits);
  __syncthreads();
  if (threadIdx.x == 0) *flag = (cnt < 512) ? 1u : 0u;   // 1 = fp32 inputs
}

// ---------------- K1: canonicalize float tensor to bf16 ----------------
__global__ void k_convert(const void* __restrict__ src, unsigned short* __restrict__ dst,
                          int n, const unsigned* __restrict__ flag) {
  int i = blockIdx.x * blockDim.x + threadIdx.x;
  if (i >= n) return;
  if (*flag) dst[i] = f2b(((const float*)src)[i]);
  else       dst[i] = ((const unsigned short*)src)[i];
}

// ---------------- K2: tag histogram scatter ----------------
__global__ void k_hist(const int* __restrict__ nid, const int* __restrict__ ntag,
                       unsigned* __restrict__ hist) {
  int e = blockIdx.x * blockDim.x + threadIdx.x;
  if (e < E_EDGESN)
    atomicAdd(&hist[(size_t)nid[e] * FEAT + ntag[e]], 1u);
}

// ---------------- K3: build x = [node_emb | nb_emb] as bf16 ----------------
__global__ __launch_bounds__(256) void k_build_x(
    const int* __restrict__ tags, const unsigned* __restrict__ hist,
    const unsigned short* __restrict__ Wemb, const unsigned short* __restrict__ bemb,
    unsigned short* __restrict__ x) {
  __shared__ int f_lds[160];
  __shared__ float c_lds[160];
  __shared__ int nlist;
  int n = blockIdx.x, c = threadIdx.x;
  if (c == 0) nlist = 0;
  __syncthreads();
  for (int f = c; f < FEAT; f += 256) {
    unsigned cnt = hist[(size_t)n * FEAT + f];
    if (cnt) {
      int idx = atomicAdd(&nlist, 1);
      if (idx < 160) { f_lds[idx] = f; c_lds[idx] = (float)cnt; }
    }
  }
  __syncthreads();
  int m = nlist; if (m > 160) m = 160;
  float be = b2f(bemb[c]);
  int tg = tags[n];
  x[(size_t)n * XDIM + c] = f2b(b2f(Wemb[(size_t)tg * EMB + c]) + be);
  float acc = be;
  for (int j = 0; j < m; ++j)
    acc += c_lds[j] * b2f(Wemb[(size_t)f_lds[j] * EMB + c]);
  x[(size_t)n * XDIM + EMB + c] = f2b(acc);
}

// ---------------- K4: pre = x @ W_ih^T + b_lstm (MFMA bf16) ----------------
// Output PERMUTED: prep[t][unit*4 + gate]; gate = nn>>9, unit = nn&511.
__global__ __launch_bounds__(256) void k_gemm_pre(
    const unsigned short* __restrict__ x, const unsigned short* __restrict__ Wih,
    const unsigned short* __restrict__ blstm, unsigned short* __restrict__ pre) {
  int wave = threadIdx.x >> 6, lane = threadIdx.x & 63;
  int row = lane & 15, quad = lane >> 4;
  int mband = blockIdx.y * 64 + wave * 16;
  int nbase = blockIdx.x * 128;
  f32x4 acc[8] = {};
  const unsigned short* ap = x + (size_t)(mband + row) * XDIM + quad * 8;
  const unsigned short* bp0 = Wih + (size_t)(nbase + row) * XDIM + quad * 8;
  for (int kc = 0; kc < 16; ++kc) {
    bf16x8 af = *(const bf16x8*)(ap + kc * 32);
#pragma unroll
    for (int nt = 0; nt < 8; ++nt) {
      bf16x8 bf = *(const bf16x8*)(bp0 + (size_t)nt * 16 * XDIM + kc * 32);
      acc[nt] = __builtin_amdgcn_mfma_f32_16x16x32_bf16(af, bf, acc[nt], 0, 0, 0);
    }
  }
#pragma unroll
  for (int nt = 0; nt < 8; ++nt) {
    int nn = nbase + nt * 16 + row;
    float bv = b2f(blstm[nn]);
    int pn = ((nn & 511) << 2) | (nn >> 9);   // unit*4 + gate
#pragma unroll
    for (int i = 0; i < 4; ++i) {
      int mm = mband + quad * 4 + i;
      pre[(size_t)mm * G4 + pn] = f2b(acc[nt][i] + bv);
    }
  }
}

// ---------------- K5: replicated-mailbox LLC LSTM scan (v12) ----------------
// Byte-identical to the r10 29.9ms kernel EXCEPT: NREP 4->8, and the replica
// stores distribute one-per-lane across s<8 (gates are computed redundantly
// on all 16 lanes -> bit-identical hn on every lane, so each lane can store
// its own replica in parallel; producer critical path unchanged).
// 32 wgs x 256 thr (1 wave/SIMD). 16-lane group owns one unit; 128 fp32
// weights in VGPRs, k interleaved k = 32j + 2s + {0,1}.
// h publication: ONE word/unit = (fp32 h & 0xFFFFFF00) | (t & 0xFF)
//   (24-bit h + 8-bit tag validated r9/r10). 8 replicas, 16 KB apart; wg g
//   polls ONLY replica g&7 (4 wgs/replica) with one 8-B agent-scope relaxed
//   atomic load per thread per try — the only fabric encoding that has ever
//   worked on this part (r3/r4/r7/r10). Cannot hang: hot path IS safe path.
// Ring safety (2 slots, 8-bit tag): per-wg skew <= 2 steps by induction;
//   slot holds tag t or t-2 only. Poison 0xAA overwritten in both slots by
//   t=1, long before tag 170 recurs.
__global__ __launch_bounds__(256, 1) void k_scan(
    const unsigned short* __restrict__ Whh, const unsigned short* __restrict__ prep,
    unsigned* __restrict__ hw, float* __restrict__ embed) {
  __shared__ float h_lds[HID];
  int tid = threadIdx.x, wg = blockIdx.x;
  int ug = tid >> 4;           // unit within wg [0,16)
  int s  = tid & 15;           // k-slice
  int lane = tid & 63;
  int unit = wg * UPW + ug;    // global unit [0,512)

  // W_hh rows for this unit's 4 gates, k interleaved: k = 32j + 2s + {0,1}
  float wreg[4][32];
#pragma unroll
  for (int g = 0; g < 4; ++g) {
    const unsigned* wp = (const unsigned*)(Whh + (size_t)(g * HID + unit) * HID);
#pragma unroll
    for (int j = 0; j < 16; ++j) {
      unsigned wv = wp[16 * j + s];        // elements 32j+2s, 32j+2s+1
      wreg[g][2 * j]     = b2f((unsigned short)(wv & 0xFFFFu));
      wreg[g][2 * j + 1] = b2f((unsigned short)(wv >> 16));
    }
  }

  // pre prefetch on s==4 lanes, 8-step blocks, shfl-broadcast each step
  unsigned pc0[8], pc1[8];
  if (s == 4) {
#pragma unroll
    for (int i = 0; i < 8; ++i) {
      const unsigned* pp = (const unsigned*)(prep + (size_t)i * G4 + (unsigned)unit * 4u);
      pc0[i] = pp[0]; pc1[i] = pp[1];
    }
  }
  int bsrc = (lane & 48) | 4;

  float cstate = 0.0f, eacc = 0.0f;
  h_lds[tid] = 0.0f;
  h_lds[256 + tid] = 0.0f;
  __syncthreads();

  unsigned myrep = (unsigned)(wg & (NREP - 1));

  for (int t = 0; t < N_NODES; ++t) {
    // ---- matvec over h(t-1): conflict-free float2, 4-way broadcast ----
    float a0 = 0.f, a1 = 0.f, a2 = 0.f, a3 = 0.f;
    const float2* hb = (const float2*)h_lds;
#pragma unroll
    for (int j = 0; j < 16; ++j) {
      float2 hv = hb[j * 16 + s];
      a0 += wreg[0][2*j] * hv.x + wreg[0][2*j+1] * hv.y;
      a1 += wreg[1][2*j] * hv.x + wreg[1][2*j+1] * hv.y;
      a2 += wreg[2][2*j] * hv.x + wreg[2][2*j+1] * hv.y;
      a3 += wreg[3][2*j] * hv.x + wreg[3][2*j+1] * hv.y;
    }
#pragma unroll
    for (int off = 1; off < 16; off <<= 1) {
      a0 += __shfl_xor(a0, off);   // all 16 lanes end with identical sums
      a1 += __shfl_xor(a1, off);
      a2 += __shfl_xor(a2, off);
      a3 += __shfl_xor(a3, off);
    }

    // broadcast this step's pre words from the s==4 prefetch lane
    unsigned w0 = __shfl(pc0[t & 7], bsrc, 64);
    unsigned w1 = __shfl(pc1[t & 7], bsrc, 64);

    // ---- gates: computed redundantly on ALL 16 lanes (identical inputs
    // -> bit-identical cstate on every lane; enables parallel replica stores)
    float gi = fast_sigmoid(a0 + b2f((unsigned short)(w0 & 0xFFFFu)));
    float gf = fast_sigmoid(a1 + b2f((unsigned short)(w0 >> 16)));
    float gg = fast_tanh   (a2 + b2f((unsigned short)(w1 & 0xFFFFu)));
    float go = fast_sigmoid(a3 + b2f((unsigned short)(w1 >> 16)));
    cstate = gf * cstate + gi * gg;
    float hn = go * fast_tanh(cstate);
    if (s == 0) eacc += hn;

    unsigned tagw = (unsigned)t & 0xFFu;
    if (t < N_NODES - 1) {
      union { float f; unsigned u; } cu; cu.f = hn;
      unsigned word = (cu.u & 0xFFFFFF00u) | tagw;
      unsigned slotw = ((unsigned)t & 1u) << 9;          // slot offset in words
      if (s < 8)   // one replica store per lane: 8 stores/unit, all parallel
        __hip_atomic_store(&hw[(unsigned)s * REPW + slotw + (unsigned)unit], word,
                           __ATOMIC_RELAXED, __HIP_MEMORY_SCOPE_AGENT);
    }
    if (s == 4 && (t & 7) == 7) {   // prefetch next 8-step pre block
#pragma unroll
      for (int i = 0; i < 8; ++i) {
        int row = t + 1 + i;
        if (row >= N_NODES) row = 0;
        const unsigned* pp = (const unsigned*)(prep + (size_t)row * G4 + (unsigned)unit * 4u);
        pc0[i] = pp[0]; pc1[i] = pp[1];
      }
    }

    if (t < N_NODES - 1) {
      // poll own replica: thread covers units 2*tid, 2*tid+1 (one 8-B load)
      unsigned long long* qp = (unsigned long long*)
          (hw + myrep * REPW + (((unsigned)t & 1u) << 9)) + tid;
      unsigned v0, v1;
      int tries = 0;
      for (;;) {
        unsigned long long v = __hip_atomic_load(qp, __ATOMIC_RELAXED,
                                                 __HIP_MEMORY_SCOPE_AGENT);
        v0 = (unsigned)v; v1 = (unsigned)(v >> 32);
        if ((((v0 ^ tagw) | (v1 ^ tagw)) & 0xFFu) == 0u) break;
        if (++tries > 128) __builtin_amdgcn_s_sleep(1);
      }
      h_lds[2 * tid]     = __uint_as_float(v0 & 0xFFFFFF00u);
      h_lds[2 * tid + 1] = __uint_as_float(v1 & 0xFFFFFF00u);
      __syncthreads();
    }
  }
  if (s == 0) embed[unit] = eacc;
}

// ---------------- K6: MLP head + log_softmax ----------------
__global__ __launch_bounds__(512) void k_head(
    const float* __restrict__ embed, const unsigned short* __restrict__ W1,
    const unsigned short* __restrict__ b1, const unsigned short* __restrict__ W2,
    const unsigned short* __restrict__ b2, void* __restrict__ out,
    const unsigned* __restrict__ flag) {
  __shared__ float e_s[HID], h1_s[HID];
  __shared__ float lg[16];
  int tid = threadIdx.x;
  e_s[tid] = embed[tid];
  __syncthreads();
  float sum = b2f(b1[tid]);
  for (int i = 0; i < HID; ++i)
    sum += e_s[i] * b2f(W1[(size_t)i * HID + tid]);
  h1_s[tid] = fmaxf(sum, 0.0f);
  __syncthreads();
  if (tid < 10) {
    float l = b2f(b2[tid]);
    for (int j = 0; j < HID; ++j)
      l += h1_s[j] * b2f(W2[(size_t)j * 10 + tid]);
    lg[tid] = l;
  }
  __syncthreads();
  if (tid == 0) {
    float m = -1e30f;
    for (int c = 0; c < 10; ++c) m = fmaxf(m, lg[c]);
    float se = 0.f;
    for (int c = 0; c < 10; ++c) se += expf(lg[c] - m);
    float lse = m + logf(se);
    if (*flag) {
      for (int c = 0; c < 10; ++c) ((float*)out)[c] = lg[c] - lse;
    } else {
      for (int c = 0; c < 10; ++c) ((unsigned short*)out)[c] = f2b(lg[c] - lse);
    }
  }
}

extern "C" void kernel_launch(void* const* d_in, const int* in_sizes, int n_in,
                              void* d_out, int out_size, void* d_ws, size_t ws_size,
                              hipStream_t stream) {
  const int* node_tags = (const int*)d_in[0];
  const int* nid = (const int*)d_in[1];
  const int* ntag = (const int*)d_in[2];
  // d_in[3] = label, unused

  char* ws = (char*)d_ws;
  unsigned short* pre  = (unsigned short*)ws;                     // 67,108,864
  unsigned short* x    = (unsigned short*)(ws + 67108864);        // 16,777,216
  unsigned*       hist = (unsigned*)(ws + 83886080);              // 33,554,432
  char* tail = ws + 117440512;
  unsigned* hw    = (unsigned*)tail;                              // 128 KB: 8 replicas x 16 KB (NOT zeroed - poison-safe, see k_scan)
  unsigned* flag  = (unsigned*)(tail + 131072);
  float*    embed = (float*)(tail + 131328);                      // 2048 B
  char* wc = tail + 135168;                                       // bf16 weight copies
  unsigned short* Wemb_c  = (unsigned short*)(wc);
  unsigned short* bemb_c  = (unsigned short*)(wc + 262144);
  unsigned short* Wih_c   = (unsigned short*)(wc + 262656);
  unsigned short* Whh_c   = (unsigned short*)(wc + 2359808);
  unsigned short* blstm_c = (unsigned short*)(wc + 4456960);
  unsigned short* W1_c    = (unsigned short*)(wc + 4461056);
  unsigned short* b1_c    = (unsigned short*)(wc + 4985344);
  unsigned short* W2_c    = (unsigned short*)(wc + 4986368);
  unsigned short* b2_c    = (unsigned short*)(wc + 4996608);

  hipMemsetAsync(hist, 0, 33554432, stream);   // hist must start at zero

  k_detect<<<1, 256, 0, stream>>>((const unsigned*)d_in[6], flag);

  struct { const void* s; unsigned short* d; int n; } cv[9] = {
    { d_in[4],  Wemb_c,  FEAT * EMB },
    { d_in[5],  bemb_c,  EMB },
    { d_in[6],  Wih_c,   G4 * XDIM },
    { d_in[7],  Whh_c,   G4 * HID },
    { d_in[8],  blstm_c, G4 },
    { d_in[9],  W1_c,    HID * HID },
    { d_in[10], b1_c,    HID },
    { d_in[11], W2_c,    HID * 10 },
    { d_in[12], b2_c,    10 },
  };
  for (int i = 0; i < 9; ++i)
    k_convert<<<(cv[i].n + 255) / 256, 256, 0, stream>>>(cv[i].s, cv[i].d, cv[i].n, flag);

  k_hist<<<E_EDGESN / 256, 256, 0, stream>>>(nid, ntag, hist);
  k_build_x<<<N_NODES, 256, 0, stream>>>(node_tags, hist, Wemb_c, bemb_c, x);
  k_gemm_pre<<<dim3(G4 / 128, N_NODES / 64), 256, 0, stream>>>(x, Wih_c, blstm_c, pre);
  k_scan<<<NWG, 256, 0, stream>>>(Whh_c, pre, hw, embed);
  k_head<<<1, 512, 0, stream>>>(embed, W1_c, b1_c, W2_c, b2_c, d_out, flag);
}

// Round 13
// 30789.835 us; speedup vs baseline: 1.2194x; 1.0234x over previous
//
#include <hip/hip_runtime.h>
#include <hip/hip_bf16.h>

#define N_NODES 16384
#define E_EDGESN (16384*32)
#define FEAT 512
#define EMB 256
#define HID 512
#define G4 2048      // 4*HID
#define XDIM 512     // 2*EMB
#define NWG 32       // worker workgroups
#define UPW 16       // hidden units per wg (16 x 32 = 512)
#define NREP 4       // mailbox replicas (r10-proven optimum)
#define REPW 4096    // replica stride in words (16 KB)

typedef __attribute__((ext_vector_type(8))) short bf16x8;
typedef __attribute__((ext_vector_type(4))) float f32x4;

__device__ __forceinline__ float b2f(unsigned short u) {
  union { unsigned int i; float f; } v; v.i = ((unsigned int)u) << 16; return v.f;
}
__device__ __forceinline__ unsigned short f2b(float f) {
  union { float f; unsigned int i; } v; v.f = f;
  unsigned int x = v.i;
  unsigned int r = (x + 0x7FFFu + ((x >> 16) & 1u)) >> 16;
  return (unsigned short)r;
}
__device__ __forceinline__ float fast_sigmoid(float x) {
  return __builtin_amdgcn_rcpf(1.0f + __expf(-x));
}
__device__ __forceinline__ float fast_tanh(float x) {
  return fmaf(-2.0f, __builtin_amdgcn_rcpf(1.0f + __expf(2.0f * x)), 1.0f);
}

// ---------------- K0: dtype detection (bf16 vs fp32 inputs) ----------------
__global__ __launch_bounds__(256) void k_detect(const unsigned* __restrict__ w,
                                                unsigned* __restrict__ flag) {
  __shared__ int cnt;
  if (threadIdx.x == 0) cnt = 0;
  __syncthreads();
  int hits = 0;
#pragma unroll
  for (int j = 0; j < 4; ++j) {
    unsigned wv = w[threadIdx.x * 4 + j];
    unsigned e = (wv >> 7) & 0xFFu;
    if ((e >= 90u && e <= 126u) || ((wv & 0xFFFFu) == 0u)) hits++;
  }
  atomicAdd(&cnt, hits);
  __syncthreads();
  if (threadIdx.x == 0) *flag = (cnt < 512) ? 1u : 0u;   // 1 = fp32 inputs
}

// ---------------- K1: canonicalize float tensor to bf16 ----------------
__global__ void k_convert(const void* __restrict__ src, unsigned short* __restrict__ dst,
                          int n, const unsigned* __restrict__ flag) {
  int i = blockIdx.x * blockDim.x + threadIdx.x;
  if (i >= n) return;
  if (*flag) dst[i] = f2b(((const float*)src)[i]);
  else       dst[i] = ((const unsigned short*)src)[i];
}

// ---------------- K2: tag histogram scatter ----------------
__global__ void k_hist(const int* __restrict__ nid, const int* __restrict__ ntag,
                       unsigned* __restrict__ hist) {
  int e = blockIdx.x * blockDim.x + threadIdx.x;
  if (e < E_EDGESN)
    atomicAdd(&hist[(size_t)nid[e] * FEAT + ntag[e]], 1u);
}

// ---------------- K3: build x = [node_emb | nb_emb] as bf16 ----------------
__global__ __launch_bounds__(256) void k_build_x(
    const int* __restrict__ tags, const unsigned* __restrict__ hist,
    const unsigned short* __restrict__ Wemb, const unsigned short* __restrict__ bemb,
    unsigned short* __restrict__ x) {
  __shared__ int f_lds[160];
  __shared__ float c_lds[160];
  __shared__ int nlist;
  int n = blockIdx.x, c = threadIdx.x;
  if (c == 0) nlist = 0;
  __syncthreads();
  for (int f = c; f < FEAT; f += 256) {
    unsigned cnt = hist[(size_t)n * FEAT + f];
    if (cnt) {
      int idx = atomicAdd(&nlist, 1);
      if (idx < 160) { f_lds[idx] = f; c_lds[idx] = (float)cnt; }
    }
  }
  __syncthreads();
  int m = nlist; if (m > 160) m = 160;
  float be = b2f(bemb[c]);
  int tg = tags[n];
  x[(size_t)n * XDIM + c] = f2b(b2f(Wemb[(size_t)tg * EMB + c]) + be);
  float acc = be;
  for (int j = 0; j < m; ++j)
    acc += c_lds[j] * b2f(Wemb[(size_t)f_lds[j] * EMB + c]);
  x[(size_t)n * XDIM + EMB + c] = f2b(acc);
}

// ---------------- K4: pre = x @ W_ih^T + b_lstm (MFMA bf16) ----------------
// Output PERMUTED: prep[t][unit*4 + gate]; gate = nn>>9, unit = nn&511.
__global__ __launch_bounds__(256) void k_gemm_pre(
    const unsigned short* __restrict__ x, const unsigned short* __restrict__ Wih,
    const unsigned short* __restrict__ blstm, unsigned short* __restrict__ pre) {
  int wave = threadIdx.x >> 6, lane = threadIdx.x & 63;
  int row = lane & 15, quad = lane >> 4;
  int mband = blockIdx.y * 64 + wave * 16;
  int nbase = blockIdx.x * 128;
  f32x4 acc[8] = {};
  const unsigned short* ap = x + (size_t)(mband + row) * XDIM + quad * 8;
  const unsigned short* bp0 = Wih + (size_t)(nbase + row) * XDIM + quad * 8;
  for (int kc = 0; kc < 16; ++kc) {
    bf16x8 af = *(const bf16x8*)(ap + kc * 32);
#pragma unroll
    for (int nt = 0; nt < 8; ++nt) {
      bf16x8 bf = *(const bf16x8*)(bp0 + (size_t)nt * 16 * XDIM + kc * 32);
      acc[nt] = __builtin_amdgcn_mfma_f32_16x16x32_bf16(af, bf, acc[nt], 0, 0, 0);
    }
  }
#pragma unroll
  for (int nt = 0; nt < 8; ++nt) {
    int nn = nbase + nt * 16 + row;
    float bv = b2f(blstm[nn]);
    int pn = ((nn & 511) << 2) | (nn >> 9);   // unit*4 + gate
#pragma unroll
    for (int i = 0; i < 4; ++i) {
      int mm = mband + quad * 4 + i;
      pre[(size_t)mm * G4 + pn] = f2b(acc[nt][i] + bv);
    }
  }
}

// ---------------- K5: replicated-mailbox LLC LSTM scan (v13 = r10 champion) --
// Exact r10 (29.9 ms) configuration; single micro-change: the 4 replica
// stores are spread one-per-lane across s in {0,2,8,10} (r10 serialized two
// stores each on lanes 0 and 8; all 16 lanes hold bit-identical hn, so the
// spread only shortens the producer VMEM queue).
// 32 wgs x 256 thr (1 wave/SIMD). 16-lane group owns one unit; 128 fp32
// weights in VGPRs, k interleaved k = 32j + 2s + {0,1} (conflict-free
// float2 matvec, 4-way LDS broadcast).
// h publication: ONE word/unit = (fp32 h & 0xFFFFFF00) | (t & 0xFF)
//   (24-bit h + 8-bit tag validated r9/r10). NREP=4 replicas, 16 KB apart;
//   wg g polls ONLY replica g&3 with one 8-B agent-scope relaxed atomic load
//   per thread per try — the only fabric encoding that has ever worked on
//   this part (r3/r4/r7/r10/r12). Cannot hang: hot path IS the safe path.
// Ring safety (2 slots, 8-bit tag): per-wg skew <= 2 steps by induction;
//   a slot holds tag t or t-2 only. Poison 0xAA overwritten in both slots by
//   t=1, long before tag 170 recurs.
__global__ __launch_bounds__(256, 1) void k_scan(
    const unsigned short* __restrict__ Whh, const unsigned short* __restrict__ prep,
    unsigned* __restrict__ hw, float* __restrict__ embed) {
  __shared__ float h_lds[HID];
  int tid = threadIdx.x, wg = blockIdx.x;
  int ug = tid >> 4;           // unit within wg [0,16)
  int s  = tid & 15;           // k-slice
  int lane = tid & 63;
  int unit = wg * UPW + ug;    // global unit [0,512)

  // W_hh rows for this unit's 4 gates, k interleaved: k = 32j + 2s + {0,1}
  float wreg[4][32];
#pragma unroll
  for (int g = 0; g < 4; ++g) {
    const unsigned* wp = (const unsigned*)(Whh + (size_t)(g * HID + unit) * HID);
#pragma unroll
    for (int j = 0; j < 16; ++j) {
      unsigned wv = wp[16 * j + s];        // elements 32j+2s, 32j+2s+1
      wreg[g][2 * j]     = b2f((unsigned short)(wv & 0xFFFFu));
      wreg[g][2 * j + 1] = b2f((unsigned short)(wv >> 16));
    }
  }

  // pre prefetch on s==4 lanes, 8-step blocks, shfl-broadcast each step
  unsigned pc0[8], pc1[8];
  if (s == 4) {
#pragma unroll
    for (int i = 0; i < 8; ++i) {
      const unsigned* pp = (const unsigned*)(prep + (size_t)i * G4 + (unsigned)unit * 4u);
      pc0[i] = pp[0]; pc1[i] = pp[1];
    }
  }
  int bsrc = (lane & 48) | 4;

  float cstate = 0.0f, eacc = 0.0f;
  h_lds[tid] = 0.0f;
  h_lds[256 + tid] = 0.0f;
  __syncthreads();

  unsigned myrep = (unsigned)(wg & (NREP - 1));

  for (int t = 0; t < N_NODES; ++t) {
    // ---- matvec over h(t-1): conflict-free float2, 4-way broadcast ----
    float a0 = 0.f, a1 = 0.f, a2 = 0.f, a3 = 0.f;
    const float2* hb = (const float2*)h_lds;
#pragma unroll
    for (int j = 0; j < 16; ++j) {
      float2 hv = hb[j * 16 + s];
      a0 += wreg[0][2*j] * hv.x + wreg[0][2*j+1] * hv.y;
      a1 += wreg[1][2*j] * hv.x + wreg[1][2*j+1] * hv.y;
      a2 += wreg[2][2*j] * hv.x + wreg[2][2*j+1] * hv.y;
      a3 += wreg[3][2*j] * hv.x + wreg[3][2*j+1] * hv.y;
    }
#pragma unroll
    for (int off = 1; off < 16; off <<= 1) {
      a0 += __shfl_xor(a0, off);   // all 16 lanes end with identical sums
      a1 += __shfl_xor(a1, off);
      a2 += __shfl_xor(a2, off);
      a3 += __shfl_xor(a3, off);
    }

    // broadcast this step's pre words from the s==4 prefetch lane
    unsigned w0 = __shfl(pc0[t & 7], bsrc, 64);
    unsigned w1 = __shfl(pc1[t & 7], bsrc, 64);

    // ---- gates: computed redundantly on ALL 16 lanes (identical inputs
    // -> bit-identical cstate on every lane; enables parallel replica stores)
    float gi = fast_sigmoid(a0 + b2f((unsigned short)(w0 & 0xFFFFu)));
    float gf = fast_sigmoid(a1 + b2f((unsigned short)(w0 >> 16)));
    float gg = fast_tanh   (a2 + b2f((unsigned short)(w1 & 0xFFFFu)));
    float go = fast_sigmoid(a3 + b2f((unsigned short)(w1 >> 16)));
    cstate = gf * cstate + gi * gg;
    float hn = go * fast_tanh(cstate);
    if (s == 0) eacc += hn;

    unsigned tagw = (unsigned)t & 0xFFu;
    if (t < N_NODES - 1) {
      union { float f; unsigned u; } cu; cu.f = hn;
      unsigned word = (cu.u & 0xFFFFFF00u) | tagw;
      unsigned slotw = ((unsigned)t & 1u) << 9;          // slot offset in words
      // one replica store per lane: s==0 -> rep0, s==2 -> rep1,
      // s==8 -> rep2, s==10 -> rep3 (all fire in parallel)
      if ((s & 5) == 0 && s < 12) {
        unsigned rep = (unsigned)((s >> 3) * 2 + ((s >> 1) & 1));
        __hip_atomic_store(&hw[rep * REPW + slotw + (unsigned)unit], word,
                           __ATOMIC_RELAXED, __HIP_MEMORY_SCOPE_AGENT);
      }
    }
    if (s == 4 && (t & 7) == 7) {   // prefetch next 8-step pre block
#pragma unroll
      for (int i = 0; i < 8; ++i) {
        int row = t + 1 + i;
        if (row >= N_NODES) row = 0;
        const unsigned* pp = (const unsigned*)(prep + (size_t)row * G4 + (unsigned)unit * 4u);
        pc0[i] = pp[0]; pc1[i] = pp[1];
      }
    }

    if (t < N_NODES - 1) {
      // poll own replica: thread covers units 2*tid, 2*tid+1 (one 8-B load)
      unsigned long long* qp = (unsigned long long*)
          (hw + myrep * REPW + (((unsigned)t & 1u) << 9)) + tid;
      unsigned v0, v1;
      int tries = 0;
      for (;;) {
        unsigned long long v = __hip_atomic_load(qp, __ATOMIC_RELAXED,
                                                 __HIP_MEMORY_SCOPE_AGENT);
        v0 = (unsigned)v; v1 = (unsigned)(v >> 32);
        if ((((v0 ^ tagw) | (v1 ^ tagw)) & 0xFFu) == 0u) break;
        if (++tries > 128) __builtin_amdgcn_s_sleep(1);
      }
      h_lds[2 * tid]     = __uint_as_float(v0 & 0xFFFFFF00u);
      h_lds[2 * tid + 1] = __uint_as_float(v1 & 0xFFFFFF00u);
      __syncthreads();
    }
  }
  if (s == 0) embed[unit] = eacc;
}

// ---------------- K6: MLP head + log_softmax ----------------
__global__ __launch_bounds__(512) void k_head(
    const float* __restrict__ embed, const unsigned short* __restrict__ W1,
    const unsigned short* __restrict__ b1, const unsigned short* __restrict__ W2,
    const unsigned short* __restrict__ b2, void* __restrict__ out,
    const unsigned* __restrict__ flag) {
  __shared__ float e_s[HID], h1_s[HID];
  __shared__ float lg[16];
  int tid = threadIdx.x;
  e_s[tid] = embed[tid];
  __syncthreads();
  float sum = b2f(b1[tid]);
  for (int i = 0; i < HID; ++i)
    sum += e_s[i] * b2f(W1[(size_t)i * HID + tid]);
  h1_s[tid] = fmaxf(sum, 0.0f);
  __syncthreads();
  if (tid < 10) {
    float l = b2f(b2[tid]);
    for (int j = 0; j < HID; ++j)
      l += h1_s[j] * b2f(W2[(size_t)j * 10 + tid]);
    lg[tid] = l;
  }
  __syncthreads();
  if (tid == 0) {
    float m = -1e30f;
    for (int c = 0; c < 10; ++c) m = fmaxf(m, lg[c]);
    float se = 0.f;
    for (int c = 0; c < 10; ++c) se += expf(lg[c] - m);
    float lse = m + logf(se);
    if (*flag) {
      for (int c = 0; c < 10; ++c) ((float*)out)[c] = lg[c] - lse;
    } else {
      for (int c = 0; c < 10; ++c) ((unsigned short*)out)[c] = f2b(lg[c] - lse);
    }
  }
}

extern "C" void kernel_launch(void* const* d_in, const int* in_sizes, int n_in,
                              void* d_out, int out_size, void* d_ws, size_t ws_size,
                              hipStream_t stream) {
  const int* node_tags = (const int*)d_in[0];
  const int* nid = (const int*)d_in[1];
  const int* ntag = (const int*)d_in[2];
  // d_in[3] = label, unused

  char* ws = (char*)d_ws;
  unsigned short* pre  = (unsigned short*)ws;                     // 67,108,864
  unsigned short* x    = (unsigned short*)(ws + 67108864);        // 16,777,216
  unsigned*       hist = (unsigned*)(ws + 83886080);              // 33,554,432
  char* tail = ws + 117440512;
  unsigned* hw    = (unsigned*)tail;                              // 64 KB: 4 replicas x 16 KB (NOT zeroed - poison-safe, see k_scan)
  unsigned* flag  = (unsigned*)(tail + 65536);
  float*    embed = (float*)(tail + 65792);                       // 2048 B
  char* wc = tail + 69632;                                        // bf16 weight copies
  unsigned short* Wemb_c  = (unsigned short*)(wc);
  unsigned short* bemb_c  = (unsigned short*)(wc + 262144);
  unsigned short* Wih_c   = (unsigned short*)(wc + 262656);
  unsigned short* Whh_c   = (unsigned short*)(wc + 2359808);
  unsigned short* blstm_c = (unsigned short*)(wc + 4456960);
  unsigned short* W1_c    = (unsigned short*)(wc + 4461056);
  unsigned short* b1_c    = (unsigned short*)(wc + 4985344);
  unsigned short* W2_c    = (unsigned short*)(wc + 4986368);
  unsigned short* b2_c    = (unsigned short*)(wc + 4996608);

  hipMemsetAsync(hist, 0, 33554432, stream);   // hist must start at zero

  k_detect<<<1, 256, 0, stream>>>((const unsigned*)d_in[6], flag);

  struct { const void* s; unsigned short* d; int n; } cv[9] = {
    { d_in[4],  Wemb_c,  FEAT * EMB },
    { d_in[5],  bemb_c,  EMB },
    { d_in[6],  Wih_c,   G4 * XDIM },
    { d_in[7],  Whh_c,   G4 * HID },
    { d_in[8],  blstm_c, G4 },
    { d_in[9],  W1_c,    HID * HID },
    { d_in[10], b1_c,    HID },
    { d_in[11], W2_c,    HID * 10 },
    { d_in[12], b2_c,    10 },
  };
  for (int i = 0; i < 9; ++i)
    k_convert<<<(cv[i].n + 255) / 256, 256, 0, stream>>>(cv[i].s, cv[i].d, cv[i].n, flag);

  k_hist<<<E_EDGESN / 256, 256, 0, stream>>>(nid, ntag, hist);
  k_build_x<<<N_NODES, 256, 0, stream>>>(node_tags, hist, Wemb_c, bemb_c, x);
  k_gemm_pre<<<dim3(G4 / 128, N_NODES / 64), 256, 0, stream>>>(x, Wih_c, blstm_c, pre);
  k_scan<<<NWG, 256, 0, stream>>>(Whh_c, pre, hw, embed);
  k_head<<<1, 512, 0, stream>>>(embed, W1_c, b1_c, W2_c, b2_c, d_out, flag);
}